// Round 21
// baseline (275.196 us; speedup 1.0000x reference)
//
#include <hip/hip_runtime.h>
#include <stdint.h>
#include <string.h>

#define NNODES 100000
#define NEDGES 1000000
#define DD 64
#define DD2 128
#define CAP 32
#define NT 64
#define NTILES ((NNODES + NT - 1) / NT)
#define RS_G 8
#define RS_RANGE ((NNODES + RS_G - 1) / RS_G)   // 12500
#define NBLK 2048
#define LN2F 0.6931471805599453f

typedef __attribute__((ext_vector_type(8))) short s16x8;
typedef __attribute__((ext_vector_type(4))) float f32x4;

__device__ __forceinline__ int get_xcd() {
    unsigned v;
    asm volatile("s_getreg_b32 %0, hwreg(HW_REG_XCC_ID)" : "=s"(v));
    return (int)(v & 7u);
}

__device__ __forceinline__ unsigned bf16pack(float a, float b) {
    unsigned ua = __float_as_uint(a);
    unsigned ub = __float_as_uint(b);
    ua = (ua + 0x7fffu + ((ua >> 16) & 1u)) >> 16;
    ub = (ub + 0x7fffu + ((ub >> 16) & 1u)) >> 16;
    return ua | (ub << 16);
}
__device__ __forceinline__ unsigned short bf16of(float a) {
    unsigned ua = __float_as_uint(a);
    return (unsigned short)((ua + 0x7fffu + ((ua >> 16) & 1u)) >> 16);
}
__device__ __forceinline__ s16x8 as_s16x8(uint4 u) { union { uint4 a; s16x8 b; } c; c.a = u; return c.b; }

__device__ __forceinline__ unsigned f16pack(float a, float b) {
    _Float16 ha = (_Float16)a, hb = (_Float16)b;
    unsigned short ua, ub;
    __builtin_memcpy(&ua, &ha, 2);
    __builtin_memcpy(&ub, &hb, 2);
    return (unsigned)ua | ((unsigned)ub << 16);
}
__device__ __forceinline__ float f16lo(unsigned u) {
    unsigned short v = (unsigned short)(u & 0xffffu);
    _Float16 h;
    __builtin_memcpy(&h, &v, 2);
    return (float)h;
}
__device__ __forceinline__ float f16hi(unsigned u) {
    unsigned short v = (unsigned short)(u >> 16);
    _Float16 h;
    __builtin_memcpy(&h, &v, 2);
    return (float)h;
}

// ---------------- fused: pre_ep + weight prep + scatter (XCD-owned node ranges,
// per-XCD chunk queue so ownership tracks the PHYSICAL XCD of each block).
__global__ void __launch_bounds__(256) prep_scatter_kernel(
        const float* __restrict__ x, unsigned* __restrict__ EP,
        const float* __restrict__ W1, const float* __restrict__ W2,
        unsigned short* __restrict__ W1T, unsigned short* __restrict__ W2T,
        const int* __restrict__ ei, int* __restrict__ cnt, int* __restrict__ slots,
        int* __restrict__ qscat) {
    const int gsz = NBLK * 256;
    // --- pre_ep slice (grid-strided, XCD-agnostic)
    for (int q = blockIdx.x * 256 + threadIdx.x; q < NNODES * (DD / 8) + 8; q += gsz) {
        if (q < NNODES * (DD / 8)) {
            float4 v0 = ((const float4*)x)[q * 2];
            float4 v1 = ((const float4*)x)[q * 2 + 1];
            float m0 = fmaxf(v0.x, 0.f) + 1e-7f, m1 = fmaxf(v0.y, 0.f) + 1e-7f;
            float m2 = fmaxf(v0.z, 0.f) + 1e-7f, m3 = fmaxf(v0.w, 0.f) + 1e-7f;
            float m4 = fmaxf(v1.x, 0.f) + 1e-7f, m5 = fmaxf(v1.y, 0.f) + 1e-7f;
            float m6 = fmaxf(v1.z, 0.f) + 1e-7f, m7 = fmaxf(v1.w, 0.f) + 1e-7f;
            uint4 u;
            u.x = f16pack(__expf(m0), __expf(m1));
            u.y = f16pack(__expf(m2), __expf(m3));
            u.z = f16pack(__expf(m4), __expf(m5));
            u.w = f16pack(__expf(m6), __expf(m7));
            ((uint4*)EP)[q] = u;
        } else {
            ((uint4*)EP)[q] = (uint4){0x00010001u, 0x00010001u, 0x00010001u, 0x00010001u};
        }
    }
    // --- weight prep slice
    for (int i = blockIdx.x * 256 + threadIdx.x; i < 2 * DD * DD2; i += gsz) {
        if (i < DD * DD2) {
            int k = i >> 7, c = i & 127;
            W1T[c * DD + k] = bf16of(W1[i]);
        } else {
            int j = i - DD * DD2;
            int k = j >> 6, c = j & 63;
            W2T[c * DD2 + k] = bf16of(W2[j]);
        }
    }
    // --- scatter: this block serves ITS OWN XCD's node range; work via chunk queue.
    const int xcd = get_xcd();
    const int lo = xcd * RS_RANGE;
    const int hi = min(lo + RS_RANGE, NNODES);
    const int NCH = (NEDGES / 4 + 255) / 256;   // 977 chunks of 1024 edges
    __shared__ int sChunk;
    for (;;) {
        __syncthreads();
        if (threadIdx.x == 0) sChunk = atomicAdd(&qscat[xcd], 1);
        __syncthreads();
        const int c = sChunk;
        if (c >= NCH) break;
        const int e4 = c * 256 + threadIdx.x;
        if (e4 < NEDGES / 4) {
            int4 t = *(const int4*)&ei[NEDGES + e4 * 4];
            bool ix = (t.x >= lo && t.x < hi);
            bool iy = (t.y >= lo && t.y < hi);
            bool iz = (t.z >= lo && t.z < hi);
            bool iw = (t.w >= lo && t.w < hi);
            if (ix | iy | iz | iw) {
                int4 s = *(const int4*)&ei[e4 * 4];
                int p;
                if (ix) { p = atomicAdd(&cnt[t.x], 1); if (p < CAP) slots[t.x * CAP + p] = s.x; }
                if (iy) { p = atomicAdd(&cnt[t.y], 1); if (p < CAP) slots[t.y * CAP + p] = s.y; }
                if (iz) { p = atomicAdd(&cnt[t.z], 1); if (p < CAP) slots[t.z * CAP + p] = s.z; }
                if (iw) { p = atomicAdd(&cnt[t.w], 1); if (p < CAP) slots[t.w * CAP + p] = s.w; }
            }
        }
    }
}

// ---------------- softmax aggregation: XCD-owned node ranges via chunk queue;
// 4 nodes per wave, 16 gathers in flight.
__global__ void __launch_bounds__(256) agg_kernel(const float* __restrict__ x,
                                                  const unsigned* __restrict__ EP,
                                                  const int* __restrict__ cnt,
                                                  const int* __restrict__ slots,
                                                  unsigned* __restrict__ xbf_u,
                                                  int* __restrict__ qagg) {
    const int lane = threadIdx.x & 63;
    const int grp = lane >> 4;
    const int sub = lane & 15;
    const int wv = threadIdx.x >> 6;
    const int xcd = get_xcd();
    const int lo = xcd * RS_RANGE;
    const int hi = min(lo + RS_RANGE, NNODES);
    const int NCH = (RS_RANGE + 15) / 16;    // 782 chunks of 16 nodes
    const uint2* EP2 = (const uint2*)EP;
    __shared__ int sChunk;

#define ACCU(u, den, num)                                                  \
    {                                                                      \
        float E0 = f16lo(u.x), E1 = f16hi(u.x);                            \
        float E2 = f16lo(u.y), E3 = f16hi(u.y);                            \
        den.x += E0; num.x = fmaf(E0, __log2f(E0), num.x);                 \
        den.y += E1; num.y = fmaf(E1, __log2f(E1), num.y);                 \
        den.z += E2; num.z = fmaf(E2, __log2f(E2), num.z);                 \
        den.w += E3; num.w = fmaf(E3, __log2f(E3), num.w);                 \
    }
#define RED8(num, den)                                                     \
    {                                                                      \
        num.x += __shfl_xor(num.x, off, 64);                               \
        num.y += __shfl_xor(num.y, off, 64);                               \
        num.z += __shfl_xor(num.z, off, 64);                               \
        num.w += __shfl_xor(num.w, off, 64);                               \
        den.x += __shfl_xor(den.x, off, 64);                               \
        den.y += __shfl_xor(den.y, off, 64);                               \
        den.z += __shfl_xor(den.z, off, 64);                               \
        den.w += __shfl_xor(den.w, off, 64);                               \
    }

    for (;;) {
        __syncthreads();
        if (threadIdx.x == 0) sChunk = atomicAdd(&qagg[xcd], 1);
        __syncthreads();
        const int c = sChunk;
        if (c >= NCH) break;
        const int n = lo + c * 16 + wv * 4;
        if (n >= hi) continue;

        const int nA = n, nB = n + 1, nC = n + 2, nD = n + 3;
        const bool hB = nB < hi, hC = nC < hi, hD = nD < hi;
        int degA = min(cnt[nA], CAP);
        int degB = hB ? min(cnt[nB], CAP) : 0;
        int degC = hC ? min(cnt[nC], CAP) : 0;
        int degD = hD ? min(cnt[nD], CAP) : 0;
        unsigned slA = (lane < degA) ? (unsigned)slots[nA * CAP + lane] : (unsigned)NNODES;
        unsigned slB = (lane < degB) ? (unsigned)slots[nB * CAP + lane] : (unsigned)NNODES;
        unsigned slC = (lane < degC) ? (unsigned)slots[nC * CAP + lane] : (unsigned)NNODES;
        unsigned slD = (lane < degD) ? (unsigned)slots[nD * CAP + lane] : (unsigned)NNODES;

        float4 numA = {0.f,0.f,0.f,0.f}, denA = {0.f,0.f,0.f,0.f};
        float4 numB = {0.f,0.f,0.f,0.f}, denB = {0.f,0.f,0.f,0.f};
        float4 numC = {0.f,0.f,0.f,0.f}, denC = {0.f,0.f,0.f,0.f};
        float4 numD = {0.f,0.f,0.f,0.f}, denD = {0.f,0.f,0.f,0.f};

        {
            unsigned a0 = (unsigned)__shfl((int)slA, grp, 64);
            unsigned a1 = (unsigned)__shfl((int)slA, 4 + grp, 64);
            unsigned a2 = (unsigned)__shfl((int)slA, 8 + grp, 64);
            unsigned a3 = (unsigned)__shfl((int)slA, 12 + grp, 64);
            unsigned b0 = (unsigned)__shfl((int)slB, grp, 64);
            unsigned b1 = (unsigned)__shfl((int)slB, 4 + grp, 64);
            unsigned b2 = (unsigned)__shfl((int)slB, 8 + grp, 64);
            unsigned b3 = (unsigned)__shfl((int)slB, 12 + grp, 64);
            unsigned c0 = (unsigned)__shfl((int)slC, grp, 64);
            unsigned c1 = (unsigned)__shfl((int)slC, 4 + grp, 64);
            unsigned c2 = (unsigned)__shfl((int)slC, 8 + grp, 64);
            unsigned c3 = (unsigned)__shfl((int)slC, 12 + grp, 64);
            unsigned d0 = (unsigned)__shfl((int)slD, grp, 64);
            unsigned d1 = (unsigned)__shfl((int)slD, 4 + grp, 64);
            unsigned d2 = (unsigned)__shfl((int)slD, 8 + grp, 64);
            unsigned d3 = (unsigned)__shfl((int)slD, 12 + grp, 64);
            uint2 gA0 = EP2[a0 * 16u + sub];
            uint2 gA1 = EP2[a1 * 16u + sub];
            uint2 gA2 = EP2[a2 * 16u + sub];
            uint2 gA3 = EP2[a3 * 16u + sub];
            uint2 gB0 = EP2[b0 * 16u + sub];
            uint2 gB1 = EP2[b1 * 16u + sub];
            uint2 gB2 = EP2[b2 * 16u + sub];
            uint2 gB3 = EP2[b3 * 16u + sub];
            uint2 gC0 = EP2[c0 * 16u + sub];
            uint2 gC1 = EP2[c1 * 16u + sub];
            uint2 gC2 = EP2[c2 * 16u + sub];
            uint2 gC3 = EP2[c3 * 16u + sub];
            uint2 gD0 = EP2[d0 * 16u + sub];
            uint2 gD1 = EP2[d1 * 16u + sub];
            uint2 gD2 = EP2[d2 * 16u + sub];
            uint2 gD3 = EP2[d3 * 16u + sub];
            ACCU(gA0, denA, numA) ACCU(gA1, denA, numA) ACCU(gA2, denA, numA) ACCU(gA3, denA, numA)
            ACCU(gB0, denB, numB) ACCU(gB1, denB, numB) ACCU(gB2, denB, numB) ACCU(gB3, denB, numB)
            ACCU(gC0, denC, numC) ACCU(gC1, denC, numC) ACCU(gC2, denC, numC) ACCU(gC3, denC, numC)
            ACCU(gD0, denD, numD) ACCU(gD1, denD, numD) ACCU(gD2, denD, numD) ACCU(gD3, denD, numD)
        }
        if (degA > 16) {
            unsigned s0 = (unsigned)__shfl((int)slA, 16 + grp, 64);
            unsigned s1 = (unsigned)__shfl((int)slA, 20 + grp, 64);
            unsigned s2 = (unsigned)__shfl((int)slA, 24 + grp, 64);
            unsigned s3 = (unsigned)__shfl((int)slA, 28 + grp, 64);
            uint2 u0 = EP2[s0 * 16u + sub];
            uint2 u1 = EP2[s1 * 16u + sub];
            uint2 u2 = EP2[s2 * 16u + sub];
            uint2 u3 = EP2[s3 * 16u + sub];
            ACCU(u0, denA, numA) ACCU(u1, denA, numA) ACCU(u2, denA, numA) ACCU(u3, denA, numA)
        }
        if (degB > 16) {
            unsigned s0 = (unsigned)__shfl((int)slB, 16 + grp, 64);
            unsigned s1 = (unsigned)__shfl((int)slB, 20 + grp, 64);
            unsigned s2 = (unsigned)__shfl((int)slB, 24 + grp, 64);
            unsigned s3 = (unsigned)__shfl((int)slB, 28 + grp, 64);
            uint2 u0 = EP2[s0 * 16u + sub];
            uint2 u1 = EP2[s1 * 16u + sub];
            uint2 u2 = EP2[s2 * 16u + sub];
            uint2 u3 = EP2[s3 * 16u + sub];
            ACCU(u0, denB, numB) ACCU(u1, denB, numB) ACCU(u2, denB, numB) ACCU(u3, denB, numB)
        }
        if (degC > 16) {
            unsigned s0 = (unsigned)__shfl((int)slC, 16 + grp, 64);
            unsigned s1 = (unsigned)__shfl((int)slC, 20 + grp, 64);
            unsigned s2 = (unsigned)__shfl((int)slC, 24 + grp, 64);
            unsigned s3 = (unsigned)__shfl((int)slC, 28 + grp, 64);
            uint2 u0 = EP2[s0 * 16u + sub];
            uint2 u1 = EP2[s1 * 16u + sub];
            uint2 u2 = EP2[s2 * 16u + sub];
            uint2 u3 = EP2[s3 * 16u + sub];
            ACCU(u0, denC, numC) ACCU(u1, denC, numC) ACCU(u2, denC, numC) ACCU(u3, denC, numC)
        }
        if (degD > 16) {
            unsigned s0 = (unsigned)__shfl((int)slD, 16 + grp, 64);
            unsigned s1 = (unsigned)__shfl((int)slD, 20 + grp, 64);
            unsigned s2 = (unsigned)__shfl((int)slD, 24 + grp, 64);
            unsigned s3 = (unsigned)__shfl((int)slD, 28 + grp, 64);
            uint2 u0 = EP2[s0 * 16u + sub];
            uint2 u1 = EP2[s1 * 16u + sub];
            uint2 u2 = EP2[s2 * 16u + sub];
            uint2 u3 = EP2[s3 * 16u + sub];
            ACCU(u0, denD, numD) ACCU(u1, denD, numD) ACCU(u2, denD, numD) ACCU(u3, denD, numD)
        }

#pragma unroll
        for (int off = 16; off <= 32; off <<= 1) {
            RED8(numA, denA)
            RED8(numB, denB)
            RED8(numC, denC)
            RED8(numD, denD)
        }
        {
            const int nn = n + grp;
            if (nn < hi) {
                int deg = (grp == 0) ? degA : (grp == 1) ? degB : (grp == 2) ? degC : degD;
                float4 nm = (grp == 0) ? numA : (grp == 1) ? numB : (grp == 2) ? numC : numD;
                float4 dn = (grp == 0) ? denA : (grp == 1) ? denB : (grp == 2) ? denC : denD;
                const float4 xr = *(const float4*)&x[nn * DD + sub * 4];
                bool hasdeg = deg > 0;
                float o0 = hasdeg ? fmaf(LN2F * nm.x, __builtin_amdgcn_rcpf(dn.x + 1e-16f), xr.x) : xr.x;
                float o1 = hasdeg ? fmaf(LN2F * nm.y, __builtin_amdgcn_rcpf(dn.y + 1e-16f), xr.y) : xr.y;
                float o2 = hasdeg ? fmaf(LN2F * nm.z, __builtin_amdgcn_rcpf(dn.z + 1e-16f), xr.z) : xr.z;
                float o3 = hasdeg ? fmaf(LN2F * nm.w, __builtin_amdgcn_rcpf(dn.w + 1e-16f), xr.w) : xr.w;
                uint2 pk = {bf16pack(o0, o1), bf16pack(o2, o3)};
                *(uint2*)&xbf_u[nn * 32 + sub * 2] = pk;
            }
        }
    }
#undef ACCU
#undef RED8
}

// ---------------- node1_stats: MFMA h in regs, block-level LDS reduction
__global__ void __launch_bounds__(256) node1_stats(
        const unsigned short* __restrict__ xbf,
        const unsigned* __restrict__ W1Tg,
        const float* __restrict__ b1,
        float* __restrict__ sums, float* __restrict__ sumsq) {
    __shared__ unsigned sW[4096];
    __shared__ float sRed[2][DD2];
    const int tid = threadIdx.x;
    for (int i = tid; i < 4096; i += 256) {
        unsigned v = W1Tg[i];
        int byte = i << 2;
        int c = byte >> 7;
        int w = byte & 127;
        sW[(c << 5) + ((w ^ ((c & 7) << 4)) >> 2)] = v;
    }
    if (tid < DD2) { sRed[0][tid] = 0.f; sRed[1][tid] = 0.f; }
    __syncthreads();

    const int lane = tid & 63;
    const int wv = tid >> 6;
    const int r = lane & 15;
    const int kb = lane >> 4;
    const char* xb = (const char*)xbf;

    float bb[8];
    s16x8 wfrag[16];
#pragma unroll
    for (int ct = 0; ct < 8; ++ct) {
        int c = ct * 16 + r;
        bb[ct] = b1[c];
        const char* wp = (const char*)sW + c * 128;
        wfrag[2 * ct]     = *(const s16x8*)(wp + ((kb * 16) ^ ((c & 7) << 4)));
        wfrag[2 * ct + 1] = *(const s16x8*)(wp + ((64 + kb * 16) ^ ((c & 7) << 4)));
    }

    float ts[8], tq[8];
#pragma unroll
    for (int ct = 0; ct < 8; ++ct) { ts[ct] = 0.f; tq[ct] = 0.f; }

    for (int t = blockIdx.x; t < NTILES; t += gridDim.x) {
        const int n0 = t * NT;
        int arow = n0 + wv * 16 + r;
        if (arow >= NNODES) arow = NNODES - 1;
        s16x8 af0 = as_s16x8(*(const uint4*)(xb + (size_t)arow * 128 + kb * 16));
        s16x8 af1 = as_s16x8(*(const uint4*)(xb + (size_t)arow * 128 + 64 + kb * 16));
        bool valid[4];
#pragma unroll
        for (int rg = 0; rg < 4; ++rg) valid[rg] = (n0 + wv * 16 + kb * 4 + rg) < NNODES;
#pragma unroll
        for (int ct = 0; ct < 8; ++ct) {
            f32x4 acc = (f32x4){0.f, 0.f, 0.f, 0.f};
            acc = __builtin_amdgcn_mfma_f32_16x16x32_bf16(af0, wfrag[2 * ct], acc, 0, 0, 0);
            acc = __builtin_amdgcn_mfma_f32_16x16x32_bf16(af1, wfrag[2 * ct + 1], acc, 0, 0, 0);
            float s = 0.f, q = 0.f;
#pragma unroll
            for (int rg = 0; rg < 4; ++rg) {
                if (valid[rg]) {
                    float v = acc[rg] + bb[ct];
                    s += v;
                    q = fmaf(v, v, q);
                }
            }
            ts[ct] += s;
            tq[ct] += q;
        }
    }
#pragma unroll
    for (int ct = 0; ct < 8; ++ct) {
        float s = ts[ct], q = tq[ct];
        s += __shfl_xor(s, 16, 64); s += __shfl_xor(s, 32, 64);
        q += __shfl_xor(q, 16, 64); q += __shfl_xor(q, 32, 64);
        if (kb == 0) {
            atomicAdd(&sRed[0][ct * 16 + r], s);
            atomicAdd(&sRed[1][ct * 16 + r], q);
        }
    }
    __syncthreads();
    if (tid < DD2) {
        atomicAdd(&sums[tid], sRed[0][tid]);
        atomicAdd(&sumsq[tid], sRed[1][tid]);
    }
}

// ---------------- node2: recompute h (MFMA) -> BN -> relu -> swizzled LDS transpose
// -> y = h@W2 + b2 (MFMA) -> LN -> relu -> out
__global__ void __launch_bounds__(256) node2_mfma(
        const unsigned short* __restrict__ xbf,
        const float* __restrict__ sums, const float* __restrict__ sumsq,
        const float* __restrict__ bn_g, const float* __restrict__ bn_b,
        const unsigned* __restrict__ W1Tg, const float* __restrict__ b1,
        const unsigned* __restrict__ W2Tg, const float* __restrict__ b2,
        const float* __restrict__ lng, const float* __restrict__ lnb,
        float* __restrict__ out) {
    __shared__ unsigned sW1[4096];
    __shared__ unsigned sW2[4096];
    __shared__ unsigned short sH[NT * DD2];
    const int tid = threadIdx.x;
    for (int i = tid; i < 4096; i += 256) {
        unsigned v1 = W1Tg[i];
        int byte = i << 2;
        int c1 = byte >> 7, w1 = byte & 127;
        sW1[(c1 << 5) + ((w1 ^ ((c1 & 7) << 4)) >> 2)] = v1;
        unsigned v2 = W2Tg[i];
        int c2 = byte >> 8, w2 = byte & 255;
        sW2[(c2 << 6) + ((w2 ^ ((c2 & 15) << 4)) >> 2)] = v2;
    }
    __syncthreads();

    const int lane = tid & 63;
    const int wv = tid >> 6;
    const int r = lane & 15;
    const int kb = lane >> 4;
    const char* xb = (const char*)xbf;

    float bb1[8], aA[8], aB[8];
    s16x8 w1frag[16];
    const float inv_n = 1.0f / (float)NNODES;
#pragma unroll
    for (int ct = 0; ct < 8; ++ct) {
        int c = ct * 16 + r;
        bb1[ct] = b1[c];
        float mu = sums[c] * inv_n;
        float var = sumsq[c] * inv_n - mu * mu;
        float a = rsqrtf(var + 1e-5f) * bn_g[c];
        aA[ct] = a;
        aB[ct] = bn_b[c] - mu * a;
        const char* wp = (const char*)sW1 + c * 128;
        w1frag[2 * ct]     = *(const s16x8*)(wp + ((kb * 16) ^ ((c & 7) << 4)));
        w1frag[2 * ct + 1] = *(const s16x8*)(wp + ((64 + kb * 16) ^ ((c & 7) << 4)));
    }
    float b2c[4], g[4], lb[4];
    s16x8 w2frag[16];
#pragma unroll
    for (int ct = 0; ct < 4; ++ct) {
        int c = ct * 16 + r;
        b2c[ct] = b2[c];
        g[ct] = lng[c];
        lb[ct] = lnb[c];
        const char* wp = (const char*)sW2 + c * 256;
#pragma unroll
        for (int ks = 0; ks < 4; ++ks)
            w2frag[4 * ct + ks] = *(const s16x8*)(wp + ((ks * 64 + kb * 16) ^ ((c & 15) << 4)));
    }

    for (int t = blockIdx.x; t < NTILES; t += gridDim.x) {
        const int n0 = t * NT;
        int arow = n0 + wv * 16 + r;
        if (arow >= NNODES) arow = NNODES - 1;
        s16x8 af0 = as_s16x8(*(const uint4*)(xb + (size_t)arow * 128 + kb * 16));
        s16x8 af1 = as_s16x8(*(const uint4*)(xb + (size_t)arow * 128 + 64 + kb * 16));

#pragma unroll
        for (int ct = 0; ct < 8; ++ct) {
            f32x4 acc = (f32x4){0.f, 0.f, 0.f, 0.f};
            acc = __builtin_amdgcn_mfma_f32_16x16x32_bf16(af0, w1frag[2 * ct], acc, 0, 0, 0);
            acc = __builtin_amdgcn_mfma_f32_16x16x32_bf16(af1, w1frag[2 * ct + 1], acc, 0, 0, 0);
            int c = ct * 16 + r;
#pragma unroll
            for (int rg = 0; rg < 4; ++rg) {
                int row = wv * 16 + kb * 4 + rg;
                float f = fmaxf(fmaf(acc[rg] + bb1[ct], aA[ct], aB[ct]), 0.f);
                int sl = ((c >> 3) ^ (row & 7));
                sH[row * 128 + (sl << 3) + (c & 7)] = bf16of(f);
            }
        }
        __syncthreads();

        s16x8 hfrag[4];
        {
            int row = wv * 16 + r;
#pragma unroll
            for (int ks = 0; ks < 4; ++ks) {
                int sl = (ks * 4 + kb) ^ (row & 7);
                hfrag[ks] = *(const s16x8*)&sH[row * 128 + (sl << 3)];
            }
        }
        f32x4 y[4];
#pragma unroll
        for (int ct = 0; ct < 4; ++ct) {
            y[ct] = (f32x4){0.f, 0.f, 0.f, 0.f};
#pragma unroll
            for (int ks = 0; ks < 4; ++ks)
                y[ct] = __builtin_amdgcn_mfma_f32_16x16x32_bf16(hfrag[ks], w2frag[4 * ct + ks], y[ct], 0, 0, 0);
#pragma unroll
            for (int rg = 0; rg < 4; ++rg) y[ct][rg] += b2c[ct];
        }

        float mu[4], rs[4];
#pragma unroll
        for (int rg = 0; rg < 4; ++rg) {
            float sv = 0.f, qv = 0.f;
#pragma unroll
            for (int ct = 0; ct < 4; ++ct) { float v = y[ct][rg]; sv += v; qv = fmaf(v, v, qv); }
#pragma unroll
            for (int off = 1; off < 16; off <<= 1) {
                sv += __shfl_xor(sv, off, 64);
                qv += __shfl_xor(qv, off, 64);
            }
            float m = sv * (1.0f / DD);
            float var = qv * (1.0f / DD) - m * m;
            mu[rg] = m;
            rs[rg] = rsqrtf(var + 1e-5f);
        }
#pragma unroll
        for (int ct = 0; ct < 4; ++ct) {
            int c = ct * 16 + r;
#pragma unroll
            for (int rg = 0; rg < 4; ++rg) {
                int node = n0 + wv * 16 + kb * 4 + rg;
                if (node < NNODES)
                    out[(size_t)node * DD + c] = fmaxf(fmaf((y[ct][rg] - mu[rg]) * rs[rg], g[ct], lb[ct]), 0.f);
            }
        }
        __syncthreads();
    }
}

extern "C" void kernel_launch(void* const* d_in, const int* in_sizes, int n_in,
                              void* d_out, int out_size, void* d_ws, size_t ws_size,
                              hipStream_t stream) {
    const float* x    = (const float*)d_in[0];
    const int*   ei   = (const int*)d_in[1];
    const float* W1   = (const float*)d_in[2];
    const float* b1   = (const float*)d_in[3];
    const float* bn_g = (const float*)d_in[4];
    const float* bn_b = (const float*)d_in[5];
    const float* W2   = (const float*)d_in[6];
    const float* b2   = (const float*)d_in[7];
    const float* ln_g = (const float*)d_in[8];
    const float* ln_b = (const float*)d_in[9];
    float* out = (float*)d_out;

    char* p = (char*)d_ws;
    auto alloc = [&](size_t bytes) {
        p = (char*)(((uintptr_t)p + 15) & ~(uintptr_t)15);
        char* r = p; p += bytes; return (void*)r;
    };
    // zeroed region (contiguous): cnt | sums | sumsq | qscat[8] | qagg[8]
    int*   cnt    = (int*)alloc(NNODES * 4);
    float* sums   = (float*)alloc(DD2 * 4);
    float* sumsq  = (float*)alloc(DD2 * 4);
    int*   qscat  = (int*)alloc(8 * 4);
    int*   qagg   = (int*)alloc(8 * 4);
    unsigned short* W1T = (unsigned short*)alloc(DD * DD2 * 2);
    unsigned short* W2T = (unsigned short*)alloc(DD * DD2 * 2);
    int*   slots  = (int*)alloc((size_t)NNODES * CAP * 4);      // 12.8 MB
    unsigned* EP  = (unsigned*)alloc(((size_t)NNODES * DD + DD) * 2);
    unsigned short* xbf = (unsigned short*)alloc((size_t)NNODES * DD * 2);

    hipMemsetAsync(cnt, 0, (size_t)NNODES * 4 + 2 * DD2 * 4 + 16 * 4, stream);

    prep_scatter_kernel<<<NBLK, 256, 0, stream>>>(x, EP, W1, W2, W1T, W2T,
                                                  ei, cnt, slots, qscat);
    agg_kernel<<<NBLK, 256, 0, stream>>>(x, EP, cnt, slots, (unsigned*)xbf, qagg);
    node1_stats<<<128, 256, 0, stream>>>(xbf, (const unsigned*)W1T, b1, sums, sumsq);
    node2_mfma<<<512, 256, 0, stream>>>(xbf, sums, sumsq, bn_g, bn_b,
                                        (const unsigned*)W1T, b1,
                                        (const unsigned*)W2T, b2, ln_g, ln_b, out);
}

// Round 22
// 123.742 us; speedup vs baseline: 2.2240x; 2.2240x over previous
//
#include <hip/hip_runtime.h>
#include <stdint.h>
#include <string.h>

#define NNODES 100000
#define NEDGES 1000000
#define DD 64
#define DD2 128
#define CAP 32
#define NT 64
#define NTILES ((NNODES + NT - 1) / NT)
#define RS_G 8
#define RS_RANGE ((NNODES + RS_G - 1) / RS_G)   // 12500
#define RS_NB 256
#define LN2F 0.6931471805599453f

typedef __attribute__((ext_vector_type(8))) short s16x8;
typedef __attribute__((ext_vector_type(4))) float f32x4;

__device__ __forceinline__ unsigned bf16pack(float a, float b) {
    unsigned ua = __float_as_uint(a);
    unsigned ub = __float_as_uint(b);
    ua = (ua + 0x7fffu + ((ua >> 16) & 1u)) >> 16;
    ub = (ub + 0x7fffu + ((ub >> 16) & 1u)) >> 16;
    return ua | (ub << 16);
}
__device__ __forceinline__ unsigned short bf16of(float a) {
    unsigned ua = __float_as_uint(a);
    return (unsigned short)((ua + 0x7fffu + ((ua >> 16) & 1u)) >> 16);
}
__device__ __forceinline__ s16x8 as_s16x8(uint4 u) { union { uint4 a; s16x8 b; } c; c.a = u; return c.b; }

__device__ __forceinline__ unsigned f16pack(float a, float b) {
    _Float16 ha = (_Float16)a, hb = (_Float16)b;
    unsigned short ua, ub;
    __builtin_memcpy(&ua, &ha, 2);
    __builtin_memcpy(&ub, &hb, 2);
    return (unsigned)ua | ((unsigned)ub << 16);
}
__device__ __forceinline__ float f16lo(unsigned u) {
    unsigned short v = (unsigned short)(u & 0xffffu);
    _Float16 h;
    __builtin_memcpy(&h, &v, 2);
    return (float)h;
}
__device__ __forceinline__ float f16hi(unsigned u) {
    unsigned short v = (unsigned short)(u >> 16);
    _Float16 h;
    __builtin_memcpy(&h, &v, 2);
    return (float)h;
}

// ---------------- fused: pre_ep + weight prep + scatter (workgroup-scope atomics).
__global__ void __launch_bounds__(256) prep_scatter_kernel(
        const float* __restrict__ x, unsigned* __restrict__ EP,
        const float* __restrict__ W1, const float* __restrict__ W2,
        unsigned short* __restrict__ W1T, unsigned short* __restrict__ W2T,
        const int* __restrict__ ei, int* __restrict__ cnt, int* __restrict__ slots) {
    const int gsz = RS_G * RS_NB * 256;
    for (int q = blockIdx.x * 256 + threadIdx.x; q < NNODES * (DD / 8) + 8; q += gsz) {
        if (q < NNODES * (DD / 8)) {
            float4 v0 = ((const float4*)x)[q * 2];
            float4 v1 = ((const float4*)x)[q * 2 + 1];
            float m0 = fmaxf(v0.x, 0.f) + 1e-7f, m1 = fmaxf(v0.y, 0.f) + 1e-7f;
            float m2 = fmaxf(v0.z, 0.f) + 1e-7f, m3 = fmaxf(v0.w, 0.f) + 1e-7f;
            float m4 = fmaxf(v1.x, 0.f) + 1e-7f, m5 = fmaxf(v1.y, 0.f) + 1e-7f;
            float m6 = fmaxf(v1.z, 0.f) + 1e-7f, m7 = fmaxf(v1.w, 0.f) + 1e-7f;
            uint4 u;
            u.x = f16pack(__expf(m0), __expf(m1));
            u.y = f16pack(__expf(m2), __expf(m3));
            u.z = f16pack(__expf(m4), __expf(m5));
            u.w = f16pack(__expf(m6), __expf(m7));
            ((uint4*)EP)[q] = u;
        } else {
            ((uint4*)EP)[q] = (uint4){0x00010001u, 0x00010001u, 0x00010001u, 0x00010001u};
        }
    }
    for (int i = blockIdx.x * 256 + threadIdx.x; i < 2 * DD * DD2; i += gsz) {
        if (i < DD * DD2) {
            int k = i >> 7, c = i & 127;
            W1T[c * DD + k] = bf16of(W1[i]);
        } else {
            int j = i - DD * DD2;
            int k = j >> 6, c = j & 63;
            W2T[c * DD2 + k] = bf16of(W2[j]);
        }
    }
    const int group = blockIdx.x & (RS_G - 1);
    const int blk = blockIdx.x >> 3;
    const int lo = group * RS_RANGE;
    const int hi = min(lo + RS_RANGE, NNODES);
    for (int e4 = blk * 256 + threadIdx.x; e4 < NEDGES / 4; e4 += RS_NB * 256) {
        int4 t = *(const int4*)&ei[NEDGES + e4 * 4];
        bool ix = (t.x >= lo && t.x < hi);
        bool iy = (t.y >= lo && t.y < hi);
        bool iz = (t.z >= lo && t.z < hi);
        bool iw = (t.w >= lo && t.w < hi);
        if (ix | iy | iz | iw) {
            int4 s = *(const int4*)&ei[e4 * 4];
            int p;
            if (ix) { p = __hip_atomic_fetch_add(&cnt[t.x], 1, __ATOMIC_RELAXED, __HIP_MEMORY_SCOPE_WORKGROUP); if (p < CAP) slots[t.x * CAP + p] = s.x; }
            if (iy) { p = __hip_atomic_fetch_add(&cnt[t.y], 1, __ATOMIC_RELAXED, __HIP_MEMORY_SCOPE_WORKGROUP); if (p < CAP) slots[t.y * CAP + p] = s.y; }
            if (iz) { p = __hip_atomic_fetch_add(&cnt[t.z], 1, __ATOMIC_RELAXED, __HIP_MEMORY_SCOPE_WORKGROUP); if (p < CAP) slots[t.z * CAP + p] = s.z; }
            if (iw) { p = __hip_atomic_fetch_add(&cnt[t.w], 1, __ATOMIC_RELAXED, __HIP_MEMORY_SCOPE_WORKGROUP); if (p < CAP) slots[t.w * CAP + p] = s.w; }
        }
    }
}

// ---------------- softmax aggregation: 4 nodes per wave, 16 gathers in flight
__global__ void __launch_bounds__(256) agg_kernel(const float* __restrict__ x,
                                                  const unsigned* __restrict__ EP,
                                                  const int* __restrict__ cnt,
                                                  const int* __restrict__ slots,
                                                  unsigned* __restrict__ xbf_u) {
    const int lane = threadIdx.x & 63;
    const int grp = lane >> 4;
    const int sub = lane & 15;
    const int group = blockIdx.x & (RS_G - 1);
    const int blk = blockIdx.x >> 3;
    const int lo = group * RS_RANGE;
    const int hi = min(lo + RS_RANGE, NNODES);
    const int wid0 = blk * 4 + (threadIdx.x >> 6);
    const uint2* EP2 = (const uint2*)EP;

#define ACCU(u, den, num)                                                  \
    {                                                                      \
        float E0 = f16lo(u.x), E1 = f16hi(u.x);                            \
        float E2 = f16lo(u.y), E3 = f16hi(u.y);                            \
        den.x += E0; num.x = fmaf(E0, __log2f(E0), num.x);                 \
        den.y += E1; num.y = fmaf(E1, __log2f(E1), num.y);                 \
        den.z += E2; num.z = fmaf(E2, __log2f(E2), num.z);                 \
        den.w += E3; num.w = fmaf(E3, __log2f(E3), num.w);                 \
    }
#define RED8(num, den)                                                     \
    {                                                                      \
        num.x += __shfl_xor(num.x, off, 64);                               \
        num.y += __shfl_xor(num.y, off, 64);                               \
        num.z += __shfl_xor(num.z, off, 64);                               \
        num.w += __shfl_xor(num.w, off, 64);                               \
        den.x += __shfl_xor(den.x, off, 64);                               \
        den.y += __shfl_xor(den.y, off, 64);                               \
        den.z += __shfl_xor(den.z, off, 64);                               \
        den.w += __shfl_xor(den.w, off, 64);                               \
    }

    for (int n = lo + wid0 * 4; n < hi; n += RS_NB * 16) {
        const int nA = n, nB = n + 1, nC = n + 2, nD = n + 3;
        const bool hB = nB < hi, hC = nC < hi, hD = nD < hi;
        int degA = min(cnt[nA], CAP);
        int degB = hB ? min(cnt[nB], CAP) : 0;
        int degC = hC ? min(cnt[nC], CAP) : 0;
        int degD = hD ? min(cnt[nD], CAP) : 0;
        unsigned slA = (lane < degA) ? (unsigned)slots[nA * CAP + lane] : (unsigned)NNODES;
        unsigned slB = (lane < degB) ? (unsigned)slots[nB * CAP + lane] : (unsigned)NNODES;
        unsigned slC = (lane < degC) ? (unsigned)slots[nC * CAP + lane] : (unsigned)NNODES;
        unsigned slD = (lane < degD) ? (unsigned)slots[nD * CAP + lane] : (unsigned)NNODES;

        float4 numA = {0.f,0.f,0.f,0.f}, denA = {0.f,0.f,0.f,0.f};
        float4 numB = {0.f,0.f,0.f,0.f}, denB = {0.f,0.f,0.f,0.f};
        float4 numC = {0.f,0.f,0.f,0.f}, denC = {0.f,0.f,0.f,0.f};
        float4 numD = {0.f,0.f,0.f,0.f}, denD = {0.f,0.f,0.f,0.f};

        {
            unsigned a0 = (unsigned)__shfl((int)slA, grp, 64);
            unsigned a1 = (unsigned)__shfl((int)slA, 4 + grp, 64);
            unsigned a2 = (unsigned)__shfl((int)slA, 8 + grp, 64);
            unsigned a3 = (unsigned)__shfl((int)slA, 12 + grp, 64);
            unsigned b0 = (unsigned)__shfl((int)slB, grp, 64);
            unsigned b1 = (unsigned)__shfl((int)slB, 4 + grp, 64);
            unsigned b2 = (unsigned)__shfl((int)slB, 8 + grp, 64);
            unsigned b3 = (unsigned)__shfl((int)slB, 12 + grp, 64);
            unsigned c0 = (unsigned)__shfl((int)slC, grp, 64);
            unsigned c1 = (unsigned)__shfl((int)slC, 4 + grp, 64);
            unsigned c2 = (unsigned)__shfl((int)slC, 8 + grp, 64);
            unsigned c3 = (unsigned)__shfl((int)slC, 12 + grp, 64);
            unsigned d0 = (unsigned)__shfl((int)slD, grp, 64);
            unsigned d1 = (unsigned)__shfl((int)slD, 4 + grp, 64);
            unsigned d2 = (unsigned)__shfl((int)slD, 8 + grp, 64);
            unsigned d3 = (unsigned)__shfl((int)slD, 12 + grp, 64);
            uint2 gA0 = EP2[a0 * 16u + sub];
            uint2 gA1 = EP2[a1 * 16u + sub];
            uint2 gA2 = EP2[a2 * 16u + sub];
            uint2 gA3 = EP2[a3 * 16u + sub];
            uint2 gB0 = EP2[b0 * 16u + sub];
            uint2 gB1 = EP2[b1 * 16u + sub];
            uint2 gB2 = EP2[b2 * 16u + sub];
            uint2 gB3 = EP2[b3 * 16u + sub];
            uint2 gC0 = EP2[c0 * 16u + sub];
            uint2 gC1 = EP2[c1 * 16u + sub];
            uint2 gC2 = EP2[c2 * 16u + sub];
            uint2 gC3 = EP2[c3 * 16u + sub];
            uint2 gD0 = EP2[d0 * 16u + sub];
            uint2 gD1 = EP2[d1 * 16u + sub];
            uint2 gD2 = EP2[d2 * 16u + sub];
            uint2 gD3 = EP2[d3 * 16u + sub];
            ACCU(gA0, denA, numA) ACCU(gA1, denA, numA) ACCU(gA2, denA, numA) ACCU(gA3, denA, numA)
            ACCU(gB0, denB, numB) ACCU(gB1, denB, numB) ACCU(gB2, denB, numB) ACCU(gB3, denB, numB)
            ACCU(gC0, denC, numC) ACCU(gC1, denC, numC) ACCU(gC2, denC, numC) ACCU(gC3, denC, numC)
            ACCU(gD0, denD, numD) ACCU(gD1, denD, numD) ACCU(gD2, denD, numD) ACCU(gD3, denD, numD)
        }
        if (degA > 16) {
            unsigned s0 = (unsigned)__shfl((int)slA, 16 + grp, 64);
            unsigned s1 = (unsigned)__shfl((int)slA, 20 + grp, 64);
            unsigned s2 = (unsigned)__shfl((int)slA, 24 + grp, 64);
            unsigned s3 = (unsigned)__shfl((int)slA, 28 + grp, 64);
            uint2 u0 = EP2[s0 * 16u + sub];
            uint2 u1 = EP2[s1 * 16u + sub];
            uint2 u2 = EP2[s2 * 16u + sub];
            uint2 u3 = EP2[s3 * 16u + sub];
            ACCU(u0, denA, numA) ACCU(u1, denA, numA) ACCU(u2, denA, numA) ACCU(u3, denA, numA)
        }
        if (degB > 16) {
            unsigned s0 = (unsigned)__shfl((int)slB, 16 + grp, 64);
            unsigned s1 = (unsigned)__shfl((int)slB, 20 + grp, 64);
            unsigned s2 = (unsigned)__shfl((int)slB, 24 + grp, 64);
            unsigned s3 = (unsigned)__shfl((int)slB, 28 + grp, 64);
            uint2 u0 = EP2[s0 * 16u + sub];
            uint2 u1 = EP2[s1 * 16u + sub];
            uint2 u2 = EP2[s2 * 16u + sub];
            uint2 u3 = EP2[s3 * 16u + sub];
            ACCU(u0, denB, numB) ACCU(u1, denB, numB) ACCU(u2, denB, numB) ACCU(u3, denB, numB)
        }
        if (degC > 16) {
            unsigned s0 = (unsigned)__shfl((int)slC, 16 + grp, 64);
            unsigned s1 = (unsigned)__shfl((int)slC, 20 + grp, 64);
            unsigned s2 = (unsigned)__shfl((int)slC, 24 + grp, 64);
            unsigned s3 = (unsigned)__shfl((int)slC, 28 + grp, 64);
            uint2 u0 = EP2[s0 * 16u + sub];
            uint2 u1 = EP2[s1 * 16u + sub];
            uint2 u2 = EP2[s2 * 16u + sub];
            uint2 u3 = EP2[s3 * 16u + sub];
            ACCU(u0, denC, numC) ACCU(u1, denC, numC) ACCU(u2, denC, numC) ACCU(u3, denC, numC)
        }
        if (degD > 16) {
            unsigned s0 = (unsigned)__shfl((int)slD, 16 + grp, 64);
            unsigned s1 = (unsigned)__shfl((int)slD, 20 + grp, 64);
            unsigned s2 = (unsigned)__shfl((int)slD, 24 + grp, 64);
            unsigned s3 = (unsigned)__shfl((int)slD, 28 + grp, 64);
            uint2 u0 = EP2[s0 * 16u + sub];
            uint2 u1 = EP2[s1 * 16u + sub];
            uint2 u2 = EP2[s2 * 16u + sub];
            uint2 u3 = EP2[s3 * 16u + sub];
            ACCU(u0, denD, numD) ACCU(u1, denD, numD) ACCU(u2, denD, numD) ACCU(u3, denD, numD)
        }

#pragma unroll
        for (int off = 16; off <= 32; off <<= 1) {
            RED8(numA, denA)
            RED8(numB, denB)
            RED8(numC, denC)
            RED8(numD, denD)
        }
        {
            const int nn = n + grp;
            if (nn < hi) {
                int deg = (grp == 0) ? degA : (grp == 1) ? degB : (grp == 2) ? degC : degD;
                float4 nm = (grp == 0) ? numA : (grp == 1) ? numB : (grp == 2) ? numC : numD;
                float4 dn = (grp == 0) ? denA : (grp == 1) ? denB : (grp == 2) ? denC : denD;
                const float4 xr = *(const float4*)&x[nn * DD + sub * 4];
                bool hasdeg = deg > 0;
                float o0 = hasdeg ? fmaf(LN2F * nm.x, __builtin_amdgcn_rcpf(dn.x + 1e-16f), xr.x) : xr.x;
                float o1 = hasdeg ? fmaf(LN2F * nm.y, __builtin_amdgcn_rcpf(dn.y + 1e-16f), xr.y) : xr.y;
                float o2 = hasdeg ? fmaf(LN2F * nm.z, __builtin_amdgcn_rcpf(dn.z + 1e-16f), xr.z) : xr.z;
                float o3 = hasdeg ? fmaf(LN2F * nm.w, __builtin_amdgcn_rcpf(dn.w + 1e-16f), xr.w) : xr.w;
                uint2 pk = {bf16pack(o0, o1), bf16pack(o2, o3)};
                *(uint2*)&xbf_u[nn * 32 + sub * 2] = pk;
            }
        }
    }
#undef ACCU
#undef RED8
}

// ---------------- node1_stats: MFMA h in regs, block-level LDS reduction
__global__ void __launch_bounds__(256) node1_stats(
        const unsigned short* __restrict__ xbf,
        const unsigned* __restrict__ W1Tg,
        const float* __restrict__ b1,
        float* __restrict__ sums, float* __restrict__ sumsq) {
    __shared__ unsigned sW[4096];
    __shared__ float sRed[2][DD2];
    const int tid = threadIdx.x;
    for (int i = tid; i < 4096; i += 256) {
        unsigned v = W1Tg[i];
        int byte = i << 2;
        int c = byte >> 7;
        int w = byte & 127;
        sW[(c << 5) + ((w ^ ((c & 7) << 4)) >> 2)] = v;
    }
    if (tid < DD2) { sRed[0][tid] = 0.f; sRed[1][tid] = 0.f; }
    __syncthreads();

    const int lane = tid & 63;
    const int wv = tid >> 6;
    const int r = lane & 15;
    const int kb = lane >> 4;
    const char* xb = (const char*)xbf;

    float bb[8];
    s16x8 wfrag[16];
#pragma unroll
    for (int ct = 0; ct < 8; ++ct) {
        int c = ct * 16 + r;
        bb[ct] = b1[c];
        const char* wp = (const char*)sW + c * 128;
        wfrag[2 * ct]     = *(const s16x8*)(wp + ((kb * 16) ^ ((c & 7) << 4)));
        wfrag[2 * ct + 1] = *(const s16x8*)(wp + ((64 + kb * 16) ^ ((c & 7) << 4)));
    }

    float ts[8], tq[8];
#pragma unroll
    for (int ct = 0; ct < 8; ++ct) { ts[ct] = 0.f; tq[ct] = 0.f; }

    for (int t = blockIdx.x; t < NTILES; t += gridDim.x) {
        const int n0 = t * NT;
        int arow = n0 + wv * 16 + r;
        if (arow >= NNODES) arow = NNODES - 1;
        s16x8 af0 = as_s16x8(*(const uint4*)(xb + (size_t)arow * 128 + kb * 16));
        s16x8 af1 = as_s16x8(*(const uint4*)(xb + (size_t)arow * 128 + 64 + kb * 16));
        bool valid[4];
#pragma unroll
        for (int rg = 0; rg < 4; ++rg) valid[rg] = (n0 + wv * 16 + kb * 4 + rg) < NNODES;
#pragma unroll
        for (int ct = 0; ct < 8; ++ct) {
            f32x4 acc = (f32x4){0.f, 0.f, 0.f, 0.f};
            acc = __builtin_amdgcn_mfma_f32_16x16x32_bf16(af0, wfrag[2 * ct], acc, 0, 0, 0);
            acc = __builtin_amdgcn_mfma_f32_16x16x32_bf16(af1, wfrag[2 * ct + 1], acc, 0, 0, 0);
            float s = 0.f, q = 0.f;
#pragma unroll
            for (int rg = 0; rg < 4; ++rg) {
                if (valid[rg]) {
                    float v = acc[rg] + bb[ct];
                    s += v;
                    q = fmaf(v, v, q);
                }
            }
            ts[ct] += s;
            tq[ct] += q;
        }
    }
#pragma unroll
    for (int ct = 0; ct < 8; ++ct) {
        float s = ts[ct], q = tq[ct];
        s += __shfl_xor(s, 16, 64); s += __shfl_xor(s, 32, 64);
        q += __shfl_xor(q, 16, 64); q += __shfl_xor(q, 32, 64);
        if (kb == 0) {
            atomicAdd(&sRed[0][ct * 16 + r], s);
            atomicAdd(&sRed[1][ct * 16 + r], q);
        }
    }
    __syncthreads();
    if (tid < DD2) {
        atomicAdd(&sums[tid], sRed[0][tid]);
        atomicAdd(&sumsq[tid], sRed[1][tid]);
    }
}

// ---------------- node2: recompute h (MFMA) -> BN -> relu -> swizzled LDS transpose
// -> y = h@W2 + b2 (MFMA) -> LN -> relu -> out
__global__ void __launch_bounds__(256) node2_mfma(
        const unsigned short* __restrict__ xbf,
        const float* __restrict__ sums, const float* __restrict__ sumsq,
        const float* __restrict__ bn_g, const float* __restrict__ bn_b,
        const unsigned* __restrict__ W1Tg, const float* __restrict__ b1,
        const unsigned* __restrict__ W2Tg, const float* __restrict__ b2,
        const float* __restrict__ lng, const float* __restrict__ lnb,
        float* __restrict__ out) {
    __shared__ unsigned sW1[4096];
    __shared__ unsigned sW2[4096];
    __shared__ unsigned short sH[NT * DD2];
    const int tid = threadIdx.x;
    for (int i = tid; i < 4096; i += 256) {
        unsigned v1 = W1Tg[i];
        int byte = i << 2;
        int c1 = byte >> 7, w1 = byte & 127;
        sW1[(c1 << 5) + ((w1 ^ ((c1 & 7) << 4)) >> 2)] = v1;
        unsigned v2 = W2Tg[i];
        int c2 = byte >> 8, w2 = byte & 255;
        sW2[(c2 << 6) + ((w2 ^ ((c2 & 15) << 4)) >> 2)] = v2;
    }
    __syncthreads();

    const int lane = tid & 63;
    const int wv = tid >> 6;
    const int r = lane & 15;
    const int kb = lane >> 4;
    const char* xb = (const char*)xbf;

    float bb1[8], aA[8], aB[8];
    s16x8 w1frag[16];
    const float inv_n = 1.0f / (float)NNODES;
#pragma unroll
    for (int ct = 0; ct < 8; ++ct) {
        int c = ct * 16 + r;
        bb1[ct] = b1[c];
        float mu = sums[c] * inv_n;
        float var = sumsq[c] * inv_n - mu * mu;
        float a = rsqrtf(var + 1e-5f) * bn_g[c];
        aA[ct] = a;
        aB[ct] = bn_b[c] - mu * a;
        const char* wp = (const char*)sW1 + c * 128;
        w1frag[2 * ct]     = *(const s16x8*)(wp + ((kb * 16) ^ ((c & 7) << 4)));
        w1frag[2 * ct + 1] = *(const s16x8*)(wp + ((64 + kb * 16) ^ ((c & 7) << 4)));
    }
    float b2c[4], g[4], lb[4];
    s16x8 w2frag[16];
#pragma unroll
    for (int ct = 0; ct < 4; ++ct) {
        int c = ct * 16 + r;
        b2c[ct] = b2[c];
        g[ct] = lng[c];
        lb[ct] = lnb[c];
        const char* wp = (const char*)sW2 + c * 256;
#pragma unroll
        for (int ks = 0; ks < 4; ++ks)
            w2frag[4 * ct + ks] = *(const s16x8*)(wp + ((ks * 64 + kb * 16) ^ ((c & 15) << 4)));
    }

    for (int t = blockIdx.x; t < NTILES; t += gridDim.x) {
        const int n0 = t * NT;
        int arow = n0 + wv * 16 + r;
        if (arow >= NNODES) arow = NNODES - 1;
        s16x8 af0 = as_s16x8(*(const uint4*)(xb + (size_t)arow * 128 + kb * 16));
        s16x8 af1 = as_s16x8(*(const uint4*)(xb + (size_t)arow * 128 + 64 + kb * 16));

#pragma unroll
        for (int ct = 0; ct < 8; ++ct) {
            f32x4 acc = (f32x4){0.f, 0.f, 0.f, 0.f};
            acc = __builtin_amdgcn_mfma_f32_16x16x32_bf16(af0, w1frag[2 * ct], acc, 0, 0, 0);
            acc = __builtin_amdgcn_mfma_f32_16x16x32_bf16(af1, w1frag[2 * ct + 1], acc, 0, 0, 0);
            int c = ct * 16 + r;
#pragma unroll
            for (int rg = 0; rg < 4; ++rg) {
                int row = wv * 16 + kb * 4 + rg;
                float f = fmaxf(fmaf(acc[rg] + bb1[ct], aA[ct], aB[ct]), 0.f);
                int sl = ((c >> 3) ^ (row & 7));
                sH[row * 128 + (sl << 3) + (c & 7)] = bf16of(f);
            }
        }
        __syncthreads();

        s16x8 hfrag[4];
        {
            int row = wv * 16 + r;
#pragma unroll
            for (int ks = 0; ks < 4; ++ks) {
                int sl = (ks * 4 + kb) ^ (row & 7);
                hfrag[ks] = *(const s16x8*)&sH[row * 128 + (sl << 3)];
            }
        }
        f32x4 y[4];
#pragma unroll
        for (int ct = 0; ct < 4; ++ct) {
            y[ct] = (f32x4){0.f, 0.f, 0.f, 0.f};
#pragma unroll
            for (int ks = 0; ks < 4; ++ks)
                y[ct] = __builtin_amdgcn_mfma_f32_16x16x32_bf16(hfrag[ks], w2frag[4 * ct + ks], y[ct], 0, 0, 0);
#pragma unroll
            for (int rg = 0; rg < 4; ++rg) y[ct][rg] += b2c[ct];
        }

        float mu[4], rs[4];
#pragma unroll
        for (int rg = 0; rg < 4; ++rg) {
            float sv = 0.f, qv = 0.f;
#pragma unroll
            for (int ct = 0; ct < 4; ++ct) { float v = y[ct][rg]; sv += v; qv = fmaf(v, v, qv); }
#pragma unroll
            for (int off = 1; off < 16; off <<= 1) {
                sv += __shfl_xor(sv, off, 64);
                qv += __shfl_xor(qv, off, 64);
            }
            float m = sv * (1.0f / DD);
            float var = qv * (1.0f / DD) - m * m;
            mu[rg] = m;
            rs[rg] = rsqrtf(var + 1e-5f);
        }
#pragma unroll
        for (int ct = 0; ct < 4; ++ct) {
            int c = ct * 16 + r;
#pragma unroll
            for (int rg = 0; rg < 4; ++rg) {
                int node = n0 + wv * 16 + kb * 4 + rg;
                if (node < NNODES)
                    out[(size_t)node * DD + c] = fmaxf(fmaf((y[ct][rg] - mu[rg]) * rs[rg], g[ct], lb[ct]), 0.f);
            }
        }
        __syncthreads();
    }
}

extern "C" void kernel_launch(void* const* d_in, const int* in_sizes, int n_in,
                              void* d_out, int out_size, void* d_ws, size_t ws_size,
                              hipStream_t stream) {
    const float* x    = (const float*)d_in[0];
    const int*   ei   = (const int*)d_in[1];
    const float* W1   = (const float*)d_in[2];
    const float* b1   = (const float*)d_in[3];
    const float* bn_g = (const float*)d_in[4];
    const float* bn_b = (const float*)d_in[5];
    const float* W2   = (const float*)d_in[6];
    const float* b2   = (const float*)d_in[7];
    const float* ln_g = (const float*)d_in[8];
    const float* ln_b = (const float*)d_in[9];
    float* out = (float*)d_out;

    char* p = (char*)d_ws;
    auto alloc = [&](size_t bytes) {
        p = (char*)(((uintptr_t)p + 15) & ~(uintptr_t)15);
        char* r = p; p += bytes; return (void*)r;
    };
    int*   cnt    = (int*)alloc(NNODES * 4);
    float* sums   = (float*)alloc(DD2 * 4);
    float* sumsq  = (float*)alloc(DD2 * 4);
    unsigned short* W1T = (unsigned short*)alloc(DD * DD2 * 2);
    unsigned short* W2T = (unsigned short*)alloc(DD * DD2 * 2);
    int*   slots  = (int*)alloc((size_t)NNODES * CAP * 4);      // 12.8 MB
    unsigned* EP  = (unsigned*)alloc(((size_t)NNODES * DD + DD) * 2);
    unsigned short* xbf = (unsigned short*)alloc((size_t)NNODES * DD * 2);

    hipMemsetAsync(cnt, 0, (size_t)NNODES * 4 + 2 * DD2 * 4 + 32, stream);

    prep_scatter_kernel<<<RS_G * RS_NB, 256, 0, stream>>>(x, EP, W1, W2, W1T, W2T,
                                                          ei, cnt, slots);
    agg_kernel<<<RS_G * RS_NB, 256, 0, stream>>>(x, EP, cnt, slots, (unsigned*)xbf);
    node1_stats<<<128, 256, 0, stream>>>(xbf, (const unsigned*)W1T, b1, sums, sumsq);
    node2_mfma<<<512, 256, 0, stream>>>(xbf, sums, sumsq, bn_g, bn_b,
                                        (const unsigned*)W1T, b1,
                                        (const unsigned*)W2T, b2, ln_g, ln_b, out);
}